// Round 6
// baseline (69.822 us; speedup 1.0000x reference)
//
#include <hip/hip_runtime.h>

#define B_ 8
#define C_ 256
#define N_ 4096
#define CK 32
#define CG 128
#define M_ 1024

typedef __attribute__((ext_vector_type(8))) short bf16x8;
typedef __attribute__((ext_vector_type(4))) float f32x4;

__device__ __forceinline__ short f2bf(float f) {
  union { float f; unsigned u; } v; v.f = f;
  unsigned r = (v.u + 0x7FFF + ((v.u >> 16) & 1)) >> 16;  // RNE
  return (short)r;
}
__device__ __forceinline__ int packbf2(float a, float b) {
  return (f2bf(a) & 0xFFFF) | (f2bf(b) << 16);
}
__device__ __forceinline__ int cvtpk(float lo, float hi) {
  int r;
  asm("v_cvt_pk_bf16_f32 %0, %1, %2" : "=v"(r) : "v"(lo), "v"(hi));
  return r;
}
__device__ __forceinline__ float2 bf2f(int u) {
  union { int i; float f; } a, b;
  a.i = u << 16; b.i = u & 0xFFFF0000;
  return make_float2(a.f, b.f);
}

// ---------------- weight pre-convert: f32 -> bf16, once per launch
__global__ __launch_bounds__(256) void prep_kernel(const float* __restrict__ wt,
                                                   const float* __restrict__ wp,
                                                   const float* __restrict__ wg,
                                                   const float* __restrict__ wo,
                                                   short* __restrict__ wcat,
                                                   short* __restrict__ wo_bf) {
  int i = (blockIdx.x * 256 + threadIdx.x) * 4;
  const float* src;
  short* dst;
  int off;
  if (i < 8192)        { src = wt; dst = wcat;         off = i; }
  else if (i < 16384)  { src = wp; dst = wcat + 8192;  off = i - 8192; }
  else if (i < 49152)  { src = wg; dst = wcat + 16384; off = i - 16384; }
  else                 { src = wo; dst = wo_bf;        off = i - 49152; }
  float4 v = *(const float4*)(src + off);
  int2 p;
  p.x = packbf2(v.x, v.y);
  p.y = packbf2(v.z, v.w);
  *(int2*)(dst + off) = p;
}

// ---------------- fused projection: theta (unpooled) + phi/g (2x2 maxpooled)
__global__ __launch_bounds__(512) void proj_kernel(const float* __restrict__ x,
                                                   const short* __restrict__ wcat,
                                                   short* __restrict__ theta_t,
                                                   short* __restrict__ phi_t,
                                                   short* __restrict__ g_bf) {
  __shared__ __align__(16) short w_s[192 * 256];  // 96 KB, 16B-group swizzle g^(o&7)
  __shared__ __align__(16) short x_s[64 * 256];   // 32 KB, 16B-group swizzle g^(nl&7)
  int tid = threadIdx.x;
  int bx = blockIdx.x, b = blockIdx.y;
  int t = bx >> 1, half = bx & 1;

#pragma unroll
  for (int rep = 0; rep < 12; ++rep) {
    int idx = rep * 512 + tid;
    int o = idx >> 5, gp = idx & 31;
    int4 v = *(const int4*)&wcat[o * 256 + gp * 8];
    *(int4*)&w_s[o * 256 + ((gp ^ (o & 7)) * 8)] = v;
  }
  {
    int l = tid & 63, cq = tid >> 6;
    int xoff = l >> 1, dy = l & 1;
    int n = t * 128 + dy * 64 + half * 32 + xoff;
    const float* xb = x + (size_t)b * C_ * N_ + n;
#pragma unroll
    for (int rep = 0; rep < 2; ++rep) {
      int ch = cq + rep * 8;
      int c0 = ch * 16;
      float f[16];
#pragma unroll
      for (int i = 0; i < 16; ++i) f[i] = xb[(size_t)(c0 + i) * N_];
      int4 pa, pb;
      pa.x = cvtpk(f[0], f[1]);   pa.y = cvtpk(f[2], f[3]);
      pa.z = cvtpk(f[4], f[5]);   pa.w = cvtpk(f[6], f[7]);
      pb.x = cvtpk(f[8], f[9]);   pb.y = cvtpk(f[10], f[11]);
      pb.z = cvtpk(f[12], f[13]); pb.w = cvtpk(f[14], f[15]);
      *(int4*)&x_s[l * 256 + (((2 * ch) ^ (l & 7)) * 8)] = pa;
      *(int4*)&x_s[l * 256 + (((2 * ch + 1) ^ (l & 7)) * 8)] = pb;
    }
  }
  __syncthreads();

  int lane = tid & 63, w = tid >> 6;
  int h = lane >> 4, q = lane & 15;
  int ns = w & 3, ow = w >> 2;
  f32x4 acc[6];
#pragma unroll
  for (int j = 0; j < 6; ++j) acc[j] = (f32x4){0.f, 0.f, 0.f, 0.f};

  int nl = 16 * ns + q;
#pragma unroll
  for (int ks = 0; ks < 8; ++ks) {
    bf16x8 bfr = *(const bf16x8*)&x_s[nl * 256 + (((4 * ks + h) ^ (nl & 7)) * 8)];
#pragma unroll
    for (int j = 0; j < 6; ++j) {
      int o = 16 * (6 * ow + j) + q;
      bf16x8 afr = *(const bf16x8*)&w_s[o * 256 + (((4 * ks + h) ^ (o & 7)) * 8)];
      acc[j] = __builtin_amdgcn_mfma_f32_16x16x32_bf16(afr, bfr, acc[j], 0, 0, 0);
    }
  }

  int xoff = nl >> 1, dy = nl & 1;
  int n = t * 128 + dy * 64 + half * 32 + xoff;
  int m = t * 32 + half * 16 + (nl >> 2);
#pragma unroll
  for (int j = 0; j < 6; ++j) {
    int ot = 6 * ow + j;
    if (ot < 2) {  // theta, unpooled
      int2 pp;
      pp.x = cvtpk(acc[j][0], acc[j][1]);
      pp.y = cvtpk(acc[j][2], acc[j][3]);
      *(int2*)&theta_t[((size_t)b * N_ + n) * CK + ot * 16 + 4 * h] = pp;
    } else {  // pooled
      float v[4];
#pragma unroll
      for (int r = 0; r < 4; ++r) {
        float vv = acc[j][r];
        vv = fmaxf(vv, __shfl_xor(vv, 1));
        vv = fmaxf(vv, __shfl_xor(vv, 2));
        v[r] = vv;
      }
      if ((nl & 3) == 0) {
        if (ot < 4) {  // phi
          int2 pp;
          pp.x = cvtpk(v[0], v[1]);
          pp.y = cvtpk(v[2], v[3]);
          *(int2*)&phi_t[((size_t)b * M_ + m) * CK + (ot - 2) * 16 + 4 * h] = pp;
        } else {  // g
#pragma unroll
          for (int r = 0; r < 4; ++r) {
            int oc = (ot - 4) * 16 + 4 * h + r;
            g_bf[((size_t)b * CG + oc) * M_ + m] = f2bf(v[r]);
          }
        }
      }
    }
  }
}

// ---------------- flash attention, m-split 2-way (flash-decoding style)
// blockIdx.x = 2*ntile + half; each block does 8 of 16 m-tiles, writes
// unnormalized O_part (bf16) + per-query S, Mx for the merge in outproj.
__global__ __launch_bounds__(256) void attn_kernel(const short* __restrict__ theta_t,
                                                   const short* __restrict__ phi_t,
                                                   const short* __restrict__ g_bf,
                                                   short* __restrict__ o_part,
                                                   float* __restrict__ s_part,
                                                   float* __restrict__ m_part) {
  __shared__ __align__(16) short phi_s[64 * 40];   // [m][c] stride 40
  __shared__ __align__(16) short g_s[128 * 72];    // [c][m] stride 72
  __shared__ __align__(16) short p_s[4][16 * 72];  // per-wave [q][m]

  int tid = threadIdx.x;
  int lane = tid & 63, w = tid >> 6;
  int h = lane >> 4, q = lane & 15;
  int bx = blockIdx.x, b = blockIdx.y;
  int n0 = (bx >> 1) * 64, half = bx & 1;
  int n = n0 + 16 * w + q;

  bf16x8 qfrag = *(const bf16x8*)&theta_t[((size_t)b * N_ + n) * CK + 8 * h];

  f32x4 Oacc[8];
#pragma unroll
  for (int ct = 0; ct < 8; ++ct) Oacc[ct] = (f32x4){0.f, 0.f, 0.f, 0.f};
  float Mx = -INFINITY, S = 0.f;
  const f32x4 zero4 = {0.f, 0.f, 0.f, 0.f};

  int mp = tid >> 2, cpp = tid & 3;
  int mbase = half * 512;  // this block's first m

  // prologue: stage first tile
  {
    int4 v = *(const int4*)&phi_t[((size_t)b * M_ + mbase + mp) * CK + 8 * cpp];
    *(int4*)&phi_s[mp * 40 + 8 * cpp] = v;
#pragma unroll
    for (int rep = 0; rep < 4; ++rep) {
      int idx = rep * 256 + tid;
      int c = idx >> 3, mc = idx & 7;
      int4 v2 = *(const int4*)&g_bf[((size_t)b * CG + c) * M_ + mbase + 8 * mc];
      *(int4*)&g_s[c * 72 + 8 * mc] = v2;
    }
  }
  __syncthreads();

  for (int it = 0; it < 8; ++it) {
    int4 rphi, rg0, rg1, rg2, rg3;
    if (it < 7) {
      int m0n = mbase + (it + 1) * 64;
      rphi = *(const int4*)&phi_t[((size_t)b * M_ + m0n + mp) * CK + 8 * cpp];
      { int idx = tid;       int c = idx >> 3, mc = idx & 7;
        rg0 = *(const int4*)&g_bf[((size_t)b * CG + c) * M_ + m0n + 8 * mc]; }
      { int idx = 256 + tid; int c = idx >> 3, mc = idx & 7;
        rg1 = *(const int4*)&g_bf[((size_t)b * CG + c) * M_ + m0n + 8 * mc]; }
      { int idx = 512 + tid; int c = idx >> 3, mc = idx & 7;
        rg2 = *(const int4*)&g_bf[((size_t)b * CG + c) * M_ + m0n + 8 * mc]; }
      { int idx = 768 + tid; int c = idx >> 3, mc = idx & 7;
        rg3 = *(const int4*)&g_bf[((size_t)b * CG + c) * M_ + m0n + 8 * mc]; }
    }

    // QK^T
    f32x4 pt[4];
#pragma unroll
    for (int mt = 0; mt < 4; ++mt) {
      bf16x8 af = *(const bf16x8*)&phi_s[(16 * mt + q) * 40 + 8 * h];
      pt[mt] = __builtin_amdgcn_mfma_f32_16x16x32_bf16(af, qfrag, zero4, 0, 0, 0);
    }

    // online softmax, defer-max THR=8
    float pm = pt[0][0];
#pragma unroll
    for (int mt = 0; mt < 4; ++mt)
#pragma unroll
      for (int r = 0; r < 4; ++r) pm = fmaxf(pm, pt[mt][r]);
    pm = fmaxf(pm, __shfl_xor(pm, 16));
    pm = fmaxf(pm, __shfl_xor(pm, 32));
    if (!__all(pm - Mx <= 8.f)) {
      float Mn = fmaxf(Mx, pm);
      float fsc = __expf(Mx - Mn);
      S *= fsc;
#pragma unroll
      for (int ct = 0; ct < 8; ++ct) Oacc[ct] *= fsc;
      Mx = Mn;
    }
    float ps = 0.f;
#pragma unroll
    for (int mt = 0; mt < 4; ++mt) {
      float e0 = __expf(pt[mt][0] - Mx);
      float e1 = __expf(pt[mt][1] - Mx);
      float e2 = __expf(pt[mt][2] - Mx);
      float e3 = __expf(pt[mt][3] - Mx);
      ps += (e0 + e1) + (e2 + e3);
      int2 pk;
      pk.x = cvtpk(e0, e1);
      pk.y = cvtpk(e2, e3);
      *(int2*)&p_s[w][q * 72 + 16 * mt + 4 * h] = pk;
    }
    ps += __shfl_xor(ps, 16);
    ps += __shfl_xor(ps, 32);
    S += ps;

    // PV
#pragma unroll
    for (int kp = 0; kp < 2; ++kp) {
      bf16x8 pf = *(const bf16x8*)&p_s[w][q * 72 + 32 * kp + 8 * h];
#pragma unroll
      for (int ct = 0; ct < 8; ++ct) {
        bf16x8 vf = *(const bf16x8*)&g_s[(16 * ct + q) * 72 + 32 * kp + 8 * h];
        Oacc[ct] = __builtin_amdgcn_mfma_f32_16x16x32_bf16(vf, pf, Oacc[ct], 0, 0, 0);
      }
    }

    __syncthreads();
    if (it < 7) {
      *(int4*)&phi_s[mp * 40 + 8 * cpp] = rphi;
      { int idx = tid;       int c = idx >> 3, mc = idx & 7; *(int4*)&g_s[c * 72 + 8 * mc] = rg0; }
      { int idx = 256 + tid; int c = idx >> 3, mc = idx & 7; *(int4*)&g_s[c * 72 + 8 * mc] = rg1; }
      { int idx = 512 + tid; int c = idx >> 3, mc = idx & 7; *(int4*)&g_s[c * 72 + 8 * mc] = rg2; }
      { int idx = 768 + tid; int c = idx >> 3, mc = idx & 7; *(int4*)&g_s[c * 72 + 8 * mc] = rg3; }
      __syncthreads();
    }
  }

  // epilogue: unnormalized O_part + (S, Mx)
#pragma unroll
  for (int ct = 0; ct < 8; ++ct) {
    int2 pp;
    pp.x = cvtpk(Oacc[ct][0], Oacc[ct][1]);
    pp.y = cvtpk(Oacc[ct][2], Oacc[ct][3]);
    *(int2*)&o_part[(((size_t)half * B_ + b) * N_ + n) * CG + 16 * ct + 4 * h] = pp;
  }
  if (h == 0) {
    s_part[((size_t)half * B_ + b) * N_ + n] = S;
    m_part[((size_t)half * B_ + b) * N_ + n] = Mx;
  }
}

// ---------------- out projection + residual; merges the two attn halves
__global__ __launch_bounds__(512) void outproj_kernel(const short* __restrict__ o_part,
                                                      const float* __restrict__ s_part,
                                                      const float* __restrict__ m_part,
                                                      const short* __restrict__ wo_bf,
                                                      const float* __restrict__ x,
                                                      const float* __restrict__ gamma,
                                                      float* __restrict__ out) {
  __shared__ __align__(16) short wo_s[256 * 128];  // 64 KB, swizzle g^(o&7)
  __shared__ __align__(16) short ot_s[64 * 128];   // 16 KB, swizzle g^(n&7)
  __shared__ float2 c_s[64];
  int tid = threadIdx.x;
  int b = blockIdx.y, n0 = blockIdx.x * 64;

#pragma unroll
  for (int rep = 0; rep < 8; ++rep) {  // stage wo (bf16)
    int idx = rep * 512 + tid;
    int o = idx >> 4, gp = idx & 15;
    int4 v = *(const int4*)&wo_bf[o * 128 + gp * 8];
    *(int4*)&wo_s[o * 128 + ((gp ^ (o & 7)) * 8)] = v;
  }
  if (tid < 64) {  // per-n merge coefficients
    size_t i1 = (size_t)b * N_ + n0 + tid;
    size_t i2 = ((size_t)B_ + b) * N_ + n0 + tid;
    float S1 = s_part[i1], M1 = m_part[i1];
    float S2 = s_part[i2], M2 = m_part[i2];
    float Mm = fmaxf(M1, M2);
    float w1 = __expf(M1 - Mm), w2 = __expf(M2 - Mm);
    float d = 1.f / (S1 * w1 + S2 * w2);
    c_s[tid] = make_float2(w1 * d, w2 * d);
  }
  __syncthreads();

#pragma unroll
  for (int rep = 0; rep < 2; ++rep) {  // stage merged o tile: [64 n][128 c]
    int idx = rep * 512 + tid;
    int nl = idx >> 4, gp = idx & 15;
    float2 cc = c_s[nl];
    int4 v1 = *(const int4*)&o_part[(((size_t)0 * B_ + b) * N_ + n0 + nl) * CG + 8 * gp];
    int4 v2 = *(const int4*)&o_part[(((size_t)1 * B_ + b) * N_ + n0 + nl) * CG + 8 * gp];
    int4 mg;
    {
      float2 a0 = bf2f(v1.x), b0 = bf2f(v2.x);
      float2 a1 = bf2f(v1.y), b1 = bf2f(v2.y);
      mg.x = cvtpk(cc.x * a0.x + cc.y * b0.x, cc.x * a0.y + cc.y * b0.y);
      mg.y = cvtpk(cc.x * a1.x + cc.y * b1.x, cc.x * a1.y + cc.y * b1.y);
      float2 a2 = bf2f(v1.z), b2 = bf2f(v2.z);
      float2 a3 = bf2f(v1.w), b3 = bf2f(v2.w);
      mg.z = cvtpk(cc.x * a2.x + cc.y * b2.x, cc.x * a2.y + cc.y * b2.y);
      mg.w = cvtpk(cc.x * a3.x + cc.y * b3.x, cc.x * a3.y + cc.y * b3.y);
    }
    *(int4*)&ot_s[nl * 128 + ((gp ^ (nl & 7)) * 8)] = mg;
  }
  __syncthreads();

  int lane = tid & 63, w = tid >> 6;
  int h = lane >> 4, q = lane & 15;
  int ns = w & 3, oh = w >> 2;
  f32x4 acc[8];
#pragma unroll
  for (int j = 0; j < 8; ++j) acc[j] = (f32x4){0.f, 0.f, 0.f, 0.f};

  int nl = 16 * ns + q;
#pragma unroll
  for (int ks = 0; ks < 4; ++ks) {
    bf16x8 bfr = *(const bf16x8*)&ot_s[nl * 128 + (((4 * ks + h) ^ (nl & 7)) * 8)];
#pragma unroll
    for (int j = 0; j < 8; ++j) {
      int o = 128 * oh + 16 * j + q;
      bf16x8 afr = *(const bf16x8*)&wo_s[o * 128 + (((4 * ks + h) ^ (o & 7)) * 8)];
      acc[j] = __builtin_amdgcn_mfma_f32_16x16x32_bf16(afr, bfr, acc[j], 0, 0, 0);
    }
  }

  float gm = gamma[0];
  int n = n0 + 16 * ns + q;
#pragma unroll
  for (int j = 0; j < 8; ++j)
#pragma unroll
    for (int r = 0; r < 4; ++r) {
      int o = 128 * oh + 16 * j + 4 * h + r;
      size_t idx = ((size_t)b * C_ + o) * N_ + n;
      out[idx] = gm * acc[j][r] + x[idx];
    }
}

extern "C" void kernel_launch(void* const* d_in, const int* in_sizes, int n_in,
                              void* d_out, int out_size, void* d_ws, size_t ws_size,
                              hipStream_t stream) {
  const float* x = (const float*)d_in[0];
  const float* wt = (const float*)d_in[1];
  const float* wp = (const float*)d_in[2];
  const float* wg = (const float*)d_in[3];
  const float* wo = (const float*)d_in[4];
  const float* gamma = (const float*)d_in[5];
  float* out = (float*)d_out;

  short* theta_t = (short*)d_ws;                       // 8*4096*32
  short* phi_t = theta_t + (size_t)B_ * N_ * CK;       // 8*1024*32
  short* g_bf = phi_t + (size_t)B_ * M_ * CK;          // 8*128*1024
  short* o_part = g_bf + (size_t)B_ * CG * M_;         // 2*8*4096*128
  short* wcat = o_part + 2 * (size_t)B_ * N_ * CG;     // 192*256
  short* wo_bf = wcat + 192 * 256;                     // 256*128
  float* s_part = (float*)(wo_bf + 256 * 128);         // 2*8*4096
  float* m_part = s_part + 2 * (size_t)B_ * N_;        // 2*8*4096

  prep_kernel<<<dim3(80), 256, 0, stream>>>(wt, wp, wg, wo, wcat, wo_bf);
  proj_kernel<<<dim3(64, 8), 512, 0, stream>>>(x, wcat, theta_t, phi_t, g_bf);
  attn_kernel<<<dim3(128, 8), 256, 0, stream>>>(theta_t, phi_t, g_bf, o_part, s_part, m_part);
  outproj_kernel<<<dim3(64, 8), 512, 0, stream>>>(o_part, s_part, m_part, wo_bf, x, gamma, out);
}